// Round 1
// baseline (469.488 us; speedup 1.0000x reference)
//
#include <hip/hip_runtime.h>
#include <math.h>

#define N_NODES 50000
#define OUT_DIM 64

// One 64-lane wave per edge; lane index = feature dimension.
// All node-row accesses are coalesced 256B transactions.
// Output is written with non-temporal stores so the 256MB output stream
// does not evict the ~51MB of node tables from L2/L3 (the gathers re-read
// those tables with high reuse: 1.28GB of gather traffic vs 51MB of data).
__global__ __launch_bounds__(256) void edge_message_kernel(
    const float* __restrict__ G,
    const float* __restrict__ K,
    const float* __restrict__ Q,
    const float* __restrict__ V,
    const int* __restrict__ src,
    const int* __restrict__ dst,
    float* __restrict__ out,
    int nEdges)
{
    const int lane = threadIdx.x & 63;
    const int wavesPerBlock = blockDim.x >> 6;
    const int waveId = blockIdx.x * wavesPerBlock + (threadIdx.x >> 6);
    const int waveStride = gridDim.x * wavesPerBlock;
    const float inv_sqrt_d = 0.125f;  // 1/sqrt(64)

    for (int e = waveId; e < nEdges; e += waveStride) {
        // scalar (wave-uniform) index loads — broadcast, one transaction each
        const int s = __builtin_nontemporal_load(&src[e]);
        const int d = __builtin_nontemporal_load(&dst[e]);

        const float gs = G[s * OUT_DIM + lane];
        const float gd = G[d * OUT_DIM + lane];
        const float ks = K[s * OUT_DIM + lane];
        const float qd = Q[d * OUT_DIM + lane];
        const float vs = V[s * OUT_DIM + lane];

        const float df = gs - gd;
        float a = df * df;      // -> sum of squared diffs
        float b = ks * qd;      // -> dot(K_src, Q_dst)

        // simultaneous 64-lane butterfly reduction of both partials
        #pragma unroll
        for (int off = 32; off > 0; off >>= 1) {
            a += __shfl_xor(a, off, 64);
            b += __shfl_xor(b, off, 64);
        }

        const float dist  = -sqrtf(a + 1e-6f);
        float t1 = dist * inv_sqrt_d;
        t1 = fminf(fmaxf(t1, -5.0f), 5.0f);
        float t2 = b * inv_sqrt_d;
        t2 = fminf(fmaxf(t2, -5.0f), 5.0f);
        const float w = expf(t1) * expf(t2);

        __builtin_nontemporal_store(w * vs, &out[(size_t)e * OUT_DIM + lane]);
    }
}

extern "C" void kernel_launch(void* const* d_in, const int* in_sizes, int n_in,
                              void* d_out, int out_size, void* d_ws, size_t ws_size,
                              hipStream_t stream)
{
    const float* G   = (const float*)d_in[0];
    const float* K   = (const float*)d_in[1];
    const float* Q   = (const float*)d_in[2];
    const float* V   = (const float*)d_in[3];
    const int*   src = (const int*)d_in[4];
    const int*   dst = (const int*)d_in[5];
    float* out = (float*)d_out;

    const int nEdges = in_sizes[4];

    const int block = 256;                  // 4 waves/block
    const int wavesPerBlock = block / 64;
    int grid = (nEdges + wavesPerBlock - 1) / wavesPerBlock;
    if (grid > 2048) grid = 2048;           // grid-stride the rest

    edge_message_kernel<<<grid, block, 0, stream>>>(G, K, Q, V, src, dst, out, nEdges);
}

// Round 3
// 444.400 us; speedup vs baseline: 1.0565x; 1.0565x over previous
//
#include <hip/hip_runtime.h>
#include <math.h>

#define N_NODES 50000
#define OUT_DIM 64

// Native vector type: __builtin_nontemporal_store accepts this (it rejects
// HIP's float4 class type).
typedef float f32x4 __attribute__((ext_vector_type(4)));

// 16 lanes per edge (f32x4 per lane = 256B coalesced row), 4 edges per wave.
// Amortizes index loads, address arithmetic, scalar math, and cuts the
// butterfly from 6 steps (64-lane) to 4 steps (16-lane group): ~4x fewer
// wave-instructions per edge than the scalar version (VALUBusy was 58%).
__global__ __launch_bounds__(256) void edge_message_kernel(
    const float* __restrict__ G,
    const float* __restrict__ K,
    const float* __restrict__ Q,
    const float* __restrict__ V,
    const int* __restrict__ src,
    const int* __restrict__ dst,
    float* __restrict__ out,
    int nEdges)
{
    const int tid  = threadIdx.x;
    const int lane = tid & 63;
    const int grp  = lane >> 4;   // which of 4 edges this lane works on
    const int sub  = lane & 15;   // which f32x4 of the 64-dim row
    const int wavesPerBlock = blockDim.x >> 6;
    const int waveId = blockIdx.x * wavesPerBlock + (tid >> 6);
    const int waveStride = gridDim.x * wavesPerBlock;

    const f32x4* __restrict__ G4 = (const f32x4*)G;   // row stride 16
    const f32x4* __restrict__ K4 = (const f32x4*)K;
    const f32x4* __restrict__ Q4 = (const f32x4*)Q;
    const f32x4* __restrict__ V4 = (const f32x4*)V;
    f32x4* __restrict__ out4 = (f32x4*)out;

    const float inv_sqrt_d = 0.125f;  // 1/sqrt(64)

    for (int base = waveId * 4; base < nEdges; base += waveStride * 4) {
        const int e = base + grp;
        const bool valid = (e < nEdges);
        const int ec = valid ? e : (nEdges - 1);   // clamped, avoids OOB

        // all 16 lanes of a group read the same address -> HW broadcast
        const int s = __builtin_nontemporal_load(&src[ec]);
        const int d = __builtin_nontemporal_load(&dst[ec]);

        const f32x4 gs = G4[s * 16 + sub];
        const f32x4 gd = G4[d * 16 + sub];
        const f32x4 ks = K4[s * 16 + sub];
        const f32x4 qd = Q4[d * 16 + sub];
        const f32x4 vs = V4[s * 16 + sub];

        const f32x4 df = gs - gd;
        const f32x4 kq = ks * qd;
        float a = df.x * df.x + df.y * df.y + df.z * df.z + df.w * df.w;
        float b = kq.x + kq.y + kq.z + kq.w;

        // butterfly over the 16-lane group (offsets stay inside the group)
        #pragma unroll
        for (int off = 8; off > 0; off >>= 1) {
            a += __shfl_xor(a, off, 64);
            b += __shfl_xor(b, off, 64);
        }

        float t1 = -sqrtf(a + 1e-6f) * inv_sqrt_d;
        t1 = fminf(fmaxf(t1, -5.0f), 5.0f);
        float t2 = b * inv_sqrt_d;
        t2 = fminf(fmaxf(t2, -5.0f), 5.0f);
        const float w = __expf(t1 + t2);   // exp(c1)*exp(c2) == exp(c1+c2)

        if (valid) {
            __builtin_nontemporal_store(w * vs, &out4[(size_t)e * 16 + sub]);
        }
    }
}

extern "C" void kernel_launch(void* const* d_in, const int* in_sizes, int n_in,
                              void* d_out, int out_size, void* d_ws, size_t ws_size,
                              hipStream_t stream)
{
    const float* G   = (const float*)d_in[0];
    const float* K   = (const float*)d_in[1];
    const float* Q   = (const float*)d_in[2];
    const float* V   = (const float*)d_in[3];
    const int*   src = (const int*)d_in[4];
    const int*   dst = (const int*)d_in[5];
    float* out = (float*)d_out;

    const int nEdges = in_sizes[4];

    const int block = 256;                    // 4 waves/block
    const int edgesPerBlock = (block / 64) * 4;
    int grid = (nEdges + edgesPerBlock - 1) / edgesPerBlock;
    if (grid > 2048) grid = 2048;             // grid-stride the rest

    edge_message_kernel<<<grid, block, 0, stream>>>(G, K, Q, V, src, dst, out, nEdges);
}

// Round 4
// 441.239 us; speedup vs baseline: 1.0640x; 1.0072x over previous
//
#include <hip/hip_runtime.h>
#include <math.h>

#define N_NODES 50000
#define OUT_DIM 64

typedef float f32x4 __attribute__((ext_vector_type(4)));

// 16 lanes per edge-slot (f32x4/lane = 256B coalesced row), 2 edges per group
// => 8 edges per wave-iteration. All 10 row-gathers are issued before any
// reduction (MLP), and the NEXT iteration's indices are prefetched during the
// current iteration's compute, so the index->gather dependent chain is hidden.
// Round-2 evidence: VGPR=20 (no compiler pipelining), VALUBusy 13.5%, BW 50%
// => latency-bound; this buys ~2x more requests in flight per wave.
__global__ __launch_bounds__(256) void edge_message_kernel(
    const float* __restrict__ G,
    const float* __restrict__ K,
    const float* __restrict__ Q,
    const float* __restrict__ V,
    const int* __restrict__ src,
    const int* __restrict__ dst,
    float* __restrict__ out,
    int nEdges)
{
    const int tid  = threadIdx.x;
    const int lane = tid & 63;
    const int grp  = lane >> 4;   // 4 groups per wave
    const int sub  = lane & 15;   // f32x4 slot within the 64-dim row
    const int wavesPerBlock = blockDim.x >> 6;
    const int waveId = blockIdx.x * wavesPerBlock + (tid >> 6);
    const int waveStride = gridDim.x * wavesPerBlock;   // in waves
    const int iterEdges = waveStride * 8;               // edges per grid sweep

    const f32x4* __restrict__ G4 = (const f32x4*)G;   // row stride 16
    const f32x4* __restrict__ K4 = (const f32x4*)K;
    const f32x4* __restrict__ Q4 = (const f32x4*)Q;
    const f32x4* __restrict__ V4 = (const f32x4*)V;
    f32x4* __restrict__ out4 = (f32x4*)out;

    const float inv_sqrt_d = 0.125f;  // 1/sqrt(64)
    const int last = nEdges - 1;

    int base = waveId * 8;
    if (base >= nEdges) return;

    // prologue: indices for first iteration (edges base+2*grp, +1)
    int e0 = base + grp * 2;
    int e1 = e0 + 1;
    int s0 = src[min(e0, last)], d0 = dst[min(e0, last)];
    int s1 = src[min(e1, last)], d1 = dst[min(e1, last)];

    for (; base < nEdges; base += iterEdges) {
        e0 = base + grp * 2;
        e1 = e0 + 1;
        const bool v0 = (e0 < nEdges);
        const bool v1 = (e1 < nEdges);

        // ---- issue all 10 gathers up front (max requests in flight) ----
        const f32x4 gs0 = G4[s0 * 16 + sub];
        const f32x4 gd0 = G4[d0 * 16 + sub];
        const f32x4 ks0 = K4[s0 * 16 + sub];
        const f32x4 qd0 = Q4[d0 * 16 + sub];
        const f32x4 vs0 = V4[s0 * 16 + sub];
        const f32x4 gs1 = G4[s1 * 16 + sub];
        const f32x4 gd1 = G4[d1 * 16 + sub];
        const f32x4 ks1 = K4[s1 * 16 + sub];
        const f32x4 qd1 = Q4[d1 * 16 + sub];
        const f32x4 vs1 = V4[s1 * 16 + sub];

        // ---- prefetch next iteration's indices (hide idx->gather chain) ----
        const int nb = base + iterEdges;
        const int ne0 = min(nb + grp * 2, last);
        const int ne1 = min(nb + grp * 2 + 1, last);
        const int ns0 = src[ne0], nd0 = dst[ne0];
        const int ns1 = src[ne1], nd1 = dst[ne1];

        // ---- compute edge 0 ----
        {
            const f32x4 df = gs0 - gd0;
            const f32x4 kq = ks0 * qd0;
            float a = df.x * df.x + df.y * df.y + df.z * df.z + df.w * df.w;
            float b = kq.x + kq.y + kq.z + kq.w;
            #pragma unroll
            for (int off = 8; off > 0; off >>= 1) {
                a += __shfl_xor(a, off, 64);
                b += __shfl_xor(b, off, 64);
            }
            float t1 = -sqrtf(a + 1e-6f) * inv_sqrt_d;
            t1 = fminf(fmaxf(t1, -5.0f), 5.0f);
            float t2 = b * inv_sqrt_d;
            t2 = fminf(fmaxf(t2, -5.0f), 5.0f);
            const float w = __expf(t1 + t2);
            if (v0) __builtin_nontemporal_store(w * vs0, &out4[(size_t)e0 * 16 + sub]);
        }
        // ---- compute edge 1 ----
        {
            const f32x4 df = gs1 - gd1;
            const f32x4 kq = ks1 * qd1;
            float a = df.x * df.x + df.y * df.y + df.z * df.z + df.w * df.w;
            float b = kq.x + kq.y + kq.z + kq.w;
            #pragma unroll
            for (int off = 8; off > 0; off >>= 1) {
                a += __shfl_xor(a, off, 64);
                b += __shfl_xor(b, off, 64);
            }
            float t1 = -sqrtf(a + 1e-6f) * inv_sqrt_d;
            t1 = fminf(fmaxf(t1, -5.0f), 5.0f);
            float t2 = b * inv_sqrt_d;
            t2 = fminf(fmaxf(t2, -5.0f), 5.0f);
            const float w = __expf(t1 + t2);
            if (v1) __builtin_nontemporal_store(w * vs1, &out4[(size_t)e1 * 16 + sub]);
        }

        s0 = ns0; d0 = nd0; s1 = ns1; d1 = nd1;
    }
}

extern "C" void kernel_launch(void* const* d_in, const int* in_sizes, int n_in,
                              void* d_out, int out_size, void* d_ws, size_t ws_size,
                              hipStream_t stream)
{
    const float* G   = (const float*)d_in[0];
    const float* K   = (const float*)d_in[1];
    const float* Q   = (const float*)d_in[2];
    const float* V   = (const float*)d_in[3];
    const int*   src = (const int*)d_in[4];
    const int*   dst = (const int*)d_in[5];
    float* out = (float*)d_out;

    const int nEdges = in_sizes[4];

    const int block = 256;                      // 4 waves/block
    const int edgesPerBlock = (block / 64) * 8; // 8 edges per wave-iteration
    int grid = (nEdges + edgesPerBlock - 1) / edgesPerBlock;
    if (grid > 2048) grid = 2048;               // grid-stride the rest

    edge_message_kernel<<<grid, block, 0, stream>>>(G, K, Q, V, src, dst, out, nEdges);
}